// Round 1
// baseline (1464.029 us; speedup 1.0000x reference)
//
#include <hip/hip_runtime.h>

// MyConvT: masked ConvTranspose2d, B=8, Cin=192, Cout=128, H=W=64 -> OH=OW=128,
// K=5, S=2, P=2, OP=1.  out[b,co,oh,ow] = pooled_mask ? (convT + bias) : 0
// convT[b,co,oh,ow] = sum_{ci,kh,kw} x[b,ci,(oh+2-kh)/2,(ow+2-kw)/2] * w[ci,co,kh,kw]
//   (taps valid iff oh+2-kh even & ih in range; likewise for w-axis)

#define NB   8
#define CIN  192
#define COUT 128
#define H    64
#define W    64
#define OH   128
#define OW   128
#define KS   5
#define MH   132   // OH + K - 1
#define MW   132

// ---------------- mask 5x5 any-pool -> byte map [B][OH][OW] ----------------
__global__ __launch_bounds__(256) void pool_mask_k(const int* __restrict__ mask,
                                                   unsigned char* __restrict__ many) {
  int idx = blockIdx.x * 256 + threadIdx.x;
  if (idx >= NB * OH * OW) return;
  int ow = idx & (OW - 1);
  int oh = (idx >> 7) & (OH - 1);
  int b  = idx >> 14;
  const int* mp = mask + (b * MH + oh) * MW + ow;
  int any = 0;
  #pragma unroll
  for (int i = 0; i < KS; ++i)
    #pragma unroll
    for (int j = 0; j < KS; ++j)
      any |= mp[i * MW + j];
  many[idx] = (any != 0) ? 1 : 0;
}

// ------------- repack weight [ci][co][kh][kw] -> [kh][kw][ci][co] ----------
__global__ __launch_bounds__(256) void repack_w_k(const float* __restrict__ w,
                                                  float* __restrict__ wt) {
  int idx = blockIdx.x * 256 + threadIdx.x;
  if (idx >= KS * KS * CIN * COUT) return;
  int co = idx & (COUT - 1);
  int ci = (idx >> 7) % CIN;
  int t  = idx / (CIN * COUT);     // kh*KS + kw
  int kh = t / KS, kw = t % KS;
  wt[idx] = w[((ci * COUT + co) * KS + kh) * KS + kw];
}

// ---------------- main direct conv-transpose (f32 baseline) ----------------
// block: 256 threads = 128 co  x  2 ow-parity groups.
// each thread: 8 outputs along ow (stride 2, fixed parity) for one (b, oh).
__global__ __launch_bounds__(256) void convt_k(const float* __restrict__ x,
                                               const float* __restrict__ wt,
                                               const float* __restrict__ bias,
                                               const unsigned char* __restrict__ many,
                                               float* __restrict__ out) {
  const int tid = threadIdx.x;
  const int co  = tid & (COUT - 1);
  const int g   = tid >> 7;              // ow parity this thread handles
  const int bid = blockIdx.x;
  const int owb = (bid & 7) << 4;        // 16-wide ow tile base
  const int oh  = (bid >> 3) & (OH - 1);
  const int b   = bid >> 10;

  const int ph  = oh & 1;
  const int iwb = (owb >> 1) - 1;        // xv[t] caches x col (iwb + t), t in [0,10)
  const bool v0 = (iwb >= 0);
  const bool v9 = (iwb + 9 < W);

  float acc[8];
  #pragma unroll
  for (int u = 0; u < 8; ++u) acc[u] = 0.f;

  const int nkh = ph ? 2 : 3;            // kh = ph + 2*kk
  const int nkw = g  ? 2 : 3;            // kw = g  + 2*kj

  for (int kk = 0; kk < nkh; ++kk) {
    const int kh = ph + 2 * kk;
    const int ih = (oh + 2 - kh) >> 1;
    if (ih < 0 || ih >= H) continue;
    const float* __restrict__ xrow  = x + ((size_t)((b * CIN) * H + ih)) * W + iwb;
    const float* __restrict__ wbase = wt + (size_t)((kh * KS + g) * CIN) * COUT + co;
    for (int ci = 0; ci < CIN; ++ci) {
      const float* xr = xrow + (size_t)ci * (H * W);
      float xv[10];
      xv[0] = v0 ? xr[0] : 0.f;          // guard: address could be 4B before buffer
      #pragma unroll
      for (int t = 1; t < 9; ++t) xv[t] = xr[t];
      xv[9] = v9 ? xr[9] : 0.f;          // guard: address could be 4B past buffer
      const float* wr = wbase + (size_t)ci * COUT;
      #pragma unroll
      for (int kj = 0; kj < 3; ++kj) {
        if (kj >= nkw) break;
        const float wv = wr[kj * (2 * CIN * COUT)];
        const int off = 2 - kj;          // xv index offset for this kw
        #pragma unroll
        for (int u = 0; u < 8; ++u)
          acc[u] += wv * xv[u + off];
      }
    }
  }

  const float bv = bias[co];
  const unsigned char* mrow = many + (size_t)(b * OH + oh) * OW + owb + g;
  float* orow = out + ((size_t)(b * COUT + co) * OH + oh) * OW + owb + g;
  #pragma unroll
  for (int u = 0; u < 8; ++u) {
    const int j = 2 * u;
    orow[j] = mrow[j] ? (acc[u] + bv) : 0.f;
  }
}

extern "C" void kernel_launch(void* const* d_in, const int* in_sizes, int n_in,
                              void* d_out, int out_size, void* d_ws, size_t ws_size,
                              hipStream_t stream) {
  const float* x    = (const float*)d_in[0];
  const int*   mask = (const int*)d_in[1];
  const float* w    = (const float*)d_in[2];
  const float* bias = (const float*)d_in[3];
  float* out = (float*)d_out;

  // ws layout: [0, 131072) pooled-mask bytes; then repacked weights (2.46 MB f32)
  unsigned char* many = (unsigned char*)d_ws;
  float* wt = (float*)((char*)d_ws + (size_t)(NB * OH * OW));

  pool_mask_k<<<(NB * OH * OW + 255) / 256, 256, 0, stream>>>(mask, many);
  repack_w_k<<<(KS * KS * CIN * COUT + 255) / 256, 256, 0, stream>>>(w, wt);
  convt_k<<<NB * OH * (OW / 16), 256, 0, stream>>>(x, wt, bias, many, out);
}

// Round 2
// 114.575 us; speedup vs baseline: 12.7779x; 12.7779x over previous
//
#include <hip/hip_runtime.h>
#include <hip/hip_bf16.h>

// MyConvT: masked ConvTranspose2d, B=8, Cin=192, Cout=128, 64x64 -> 128x128,
// K=5, S=2, P=2, OP=1.  out = pooled_mask ? (convT(x,w) + bias) : 0
// Implicit-GEMM bf16 MFMA version: per output row (b,oh): M=128 co x N=128 ow,
// K = Cin * taps, parity-decomposed (kh≡oh mod 2; kw≡ow mod 2, ix=ox+1-kj).

#define NB   8
#define CIN  192
#define COUT 128
#define HH   64
#define WW   64
#define OHH  128
#define OWW  128
#define MH   132
#define MW   132

#define XT_ROWS 80                      // ix_mem rows per (b,iy): 0 and 65..79 zero
#define XT_IY   (XT_ROWS * CIN)         // 15360 elems
#define WT_TAP  (COUT * CIN)            // 24576 elems

// LDS layout (bytes)
#define XS_OFF 0                        // 80 rows * 64B  = 5120
#define WS_OFF 5120                     // 5 taps * 128co * 64B = 40960
#define LDS_BYTES 46080                 // epilogue overlay: 64*132*4 = 33792 <= this

typedef short bf16x8 __attribute__((ext_vector_type(8)));
typedef float f32x4  __attribute__((ext_vector_type(4)));

static __device__ __forceinline__ unsigned short f2bf(float f) {
  union { float f; unsigned int u; } a; a.f = f;
  unsigned int u = a.u;
  unsigned int r = (u + 0x7fffu + ((u >> 16) & 1u)) >> 16;   // RNE
  return (unsigned short)r;
}

#define GLOAD_LDS16(gp, lp) __builtin_amdgcn_global_load_lds(                      \
    (const __attribute__((address_space(1))) void*)(gp),                           \
    (__attribute__((address_space(3))) void*)(lp), 16, 0, 0)

// ---------------- mask 5x5 any-pool -> byte map [B][OH][OW] ----------------
__global__ __launch_bounds__(256) void pool_mask_k(const int* __restrict__ mask,
                                                   unsigned char* __restrict__ many) {
  int idx = blockIdx.x * 256 + threadIdx.x;
  if (idx >= NB * OHH * OWW) return;
  int ow = idx & (OWW - 1);
  int oh = (idx >> 7) & (OHH - 1);
  int b  = idx >> 14;
  const int* mp = mask + (b * MH + oh) * MW + ow;
  int any = 0;
  #pragma unroll
  for (int i = 0; i < 5; ++i)
    #pragma unroll
    for (int j = 0; j < 5; ++j)
      any |= mp[i * MW + j];
  many[idx] = (any != 0) ? 1 : 0;
}

// ---- x transpose: [b][ci][iy][ix] f32 -> [b][iy][ix+1][ci] bf16 (halo 0) ----
__global__ __launch_bounds__(256) void xpose_k(const float* __restrict__ x,
                                               unsigned short* __restrict__ xt) {
  const int b = blockIdx.x >> 6, iy = blockIdx.x & 63;
  const int lane = threadIdx.x & 63, wv = threadIdx.x >> 6;
  unsigned short* orow = xt + ((size_t)(b * HH + iy)) * XT_IY;

  // zero rows: 0 and 65..79  (16 rows * 192 elems = 384 16B chunks)
  for (int idx = threadIdx.x; idx < 384; idx += 256) {
    int zr = idx / 24, ch = idx % 24;
    int row = (zr == 0) ? 0 : 64 + zr;          // 0, 65..79
    *(uint4*)(orow + row * CIN + ch * 8) = make_uint4(0, 0, 0, 0);
  }
  // data rows 1..64: lane -> ix; each wave packs 6 ci-chunks of 8
  #pragma unroll
  for (int k = 0; k < 6; ++k) {
    int ci0 = (wv * 6 + k) * 8;
    unsigned short p[8];
    #pragma unroll
    for (int e = 0; e < 8; ++e)
      p[e] = f2bf(x[(((size_t)b * CIN + ci0 + e) * HH + iy) * WW + lane]);
    uint4 v;
    v.x = (unsigned)p[0] | ((unsigned)p[1] << 16);
    v.y = (unsigned)p[2] | ((unsigned)p[3] << 16);
    v.z = (unsigned)p[4] | ((unsigned)p[5] << 16);
    v.w = (unsigned)p[6] | ((unsigned)p[7] << 16);
    *(uint4*)(orow + (1 + lane) * CIN + ci0) = v;
  }
}

// ---- w repack: [ci][co][kh][kw] f32 -> [kh][kw][co][ci] bf16 ----
__global__ __launch_bounds__(256) void wpack_k(const float* __restrict__ w,
                                               unsigned short* __restrict__ wt) {
  int idx = blockIdx.x * 256 + threadIdx.x;     // 0..24575
  int ci = idx % CIN;
  int co = idx / CIN;
  const float* src = w + (size_t)(ci * COUT + co) * 25;
  #pragma unroll
  for (int t = 0; t < 25; ++t)
    wt[(size_t)t * WT_TAP + co * CIN + ci] = f2bf(src[t]);
}

// ------------------------------ main kernel --------------------------------
// grid: 1024 = (b 8) x (oh 128). block: 256 = 4 waves.
// wave w: co_half = w>>1 (m4 tiles of 16), pw = w&1 (its ow-parity, n4 tiles).
__global__ __launch_bounds__(256, 3) void convt_mfma(
    const unsigned short* __restrict__ xt, const unsigned short* __restrict__ wt,
    const float* __restrict__ bias, const unsigned char* __restrict__ many,
    float* __restrict__ out) {
  __shared__ char lds_raw[LDS_BYTES];

  const int tid = threadIdx.x, lane = tid & 63, wv = tid >> 6;
  const int b = blockIdx.x >> 7, oh = blockIdx.x & 127;
  const int ph = oh & 1, oy = oh >> 1;
  const int pw = wv & 1, coh = wv >> 1;
  const int nkh = ph ? 2 : 3, nkw = pw ? 2 : 3;
  const int l15 = lane & 15, kc = lane >> 4;

  f32x4 acc[4][4];
  #pragma unroll
  for (int i = 0; i < 4; ++i)
    #pragma unroll
    for (int j = 0; j < 4; ++j)
      acc[i][j] = (f32x4){0.f, 0.f, 0.f, 0.f};

  for (int kk = 0; kk < nkh; ++kk) {
    const int kh = ph + 2 * kk;
    const int iy = oy + 1 - kk;
    if (iy < 0 || iy >= HH) continue;           // block-uniform
    const unsigned short* xsrc = xt + (size_t)(b * HH + iy) * XT_IY;
    const unsigned short* wsrc = wt + (size_t)(kh * 5) * WT_TAP;

    for (int cic = 0; cic < 6; ++cic) {
      const int ci0 = cic * 32;
      // ---- stage: 5 x-instrs + 40 w-instrs of 1KB each, round-robin waves ----
      for (int idx = wv; idx < 45; idx += 4) {
        if (idx < 5) {
          int ixl = idx * 16 + (lane >> 2);
          int c   = lane & 3;
          int ixr = (ixl & ~1) | ((ixl ^ (ixl >> 2)) & 1);   // inverse row-swizzle
          int cr  = c ^ (ixr & 3);                           // inverse chunk-swizzle
          const unsigned short* g = xsrc + ixr * CIN + ci0 + cr * 8;
          GLOAD_LDS16(g, lds_raw + XS_OFF + idx * 1024);
        } else {
          int t = idx - 5;
          int kw = t >> 3, j = t & 7;
          int col = j * 16 + (lane >> 2);                    // co row 0..127
          int c   = lane & 3;
          int cor = (col & ~1) | ((col ^ (col >> 2)) & 1);
          int cr  = c ^ (cor & 3);
          const unsigned short* g = wsrc + (size_t)kw * WT_TAP + cor * CIN + ci0 + cr * 8;
          GLOAD_LDS16(g, lds_raw + WS_OFF + kw * 8192 + j * 1024);
        }
      }
      __syncthreads();
      // ---- compute: per parity-tap kj, A = w[kw][co][ci32], B = x[ix][ci32] ----
      #pragma unroll
      for (int kj = 0; kj < 3; ++kj) {
        if (kj < nkw) {
          const int kw = pw + 2 * kj;
          bf16x8 af[4];
          #pragma unroll
          for (int mi = 0; mi < 4; ++mi) {
            int co = coh * 64 + mi * 16 + l15;
            int off = WS_OFF + kw * 8192 + ((co * 64 + kc * 16) ^ ((co & 7) << 4));
            af[mi] = *(const bf16x8*)(lds_raw + off);
          }
          #pragma unroll
          for (int ti = 0; ti < 4; ++ti) {
            int ixm = ti * 16 + l15 + 2 - kj;                // = ox + 1 - kj + 1
            int off = XS_OFF + ((ixm * 64 + kc * 16) ^ ((ixm & 7) << 4));
            bf16x8 bfr = *(const bf16x8*)(lds_raw + off);
            #pragma unroll
            for (int mi = 0; mi < 4; ++mi)
              acc[mi][ti] = __builtin_amdgcn_mfma_f32_16x16x32_bf16(
                  af[mi], bfr, acc[mi][ti], 0, 0, 0);
          }
        }
      }
      __syncthreads();
    }
  }

  // ---- epilogue: re-interleave parities via LDS, fuse bias+mask, coalesced store
  float* eps = (float*)lds_raw;                 // [64][132] f32 overlay
  #pragma unroll
  for (int h = 0; h < 2; ++h) {
    if (coh == h) {
      #pragma unroll
      for (int mi = 0; mi < 4; ++mi)
        #pragma unroll
        for (int ti = 0; ti < 4; ++ti)
          #pragma unroll
          for (int r = 0; r < 4; ++r) {
            int row = mi * 16 + kc * 4 + r;
            int ow  = ((ti * 16 + l15) << 1) | pw;
            eps[row * 132 + ow] = acc[mi][ti][r];
          }
    }
    __syncthreads();
    {
      int r = tid >> 2, q = tid & 3;
      int co = h * 64 + r;
      float bv = bias[co];
      const unsigned char* mrow = many + ((size_t)b * OHH + oh) * OWW + q * 32;
      float* orow = out + (((size_t)(b * COUT + co)) * OHH + oh) * OWW + q * 32;
      #pragma unroll
      for (int j = 0; j < 8; ++j) {
        f32x4 v = *(const f32x4*)(eps + r * 132 + q * 32 + j * 4);
        unsigned int m4 = *(const unsigned int*)(mrow + j * 4);
        f32x4 o;
        o.x = (m4 & 0x000000FFu) ? v.x + bv : 0.f;
        o.y = (m4 & 0x0000FF00u) ? v.y + bv : 0.f;
        o.z = (m4 & 0x00FF0000u) ? v.z + bv : 0.f;
        o.w = (m4 & 0xFF000000u) ? v.w + bv : 0.f;
        *(f32x4*)(orow + j * 4) = o;
      }
    }
    __syncthreads();
  }
}

extern "C" void kernel_launch(void* const* d_in, const int* in_sizes, int n_in,
                              void* d_out, int out_size, void* d_ws, size_t ws_size,
                              hipStream_t stream) {
  const float* x    = (const float*)d_in[0];
  const int*   mask = (const int*)d_in[1];
  const float* w    = (const float*)d_in[2];
  const float* bias = (const float*)d_in[3];
  float* out = (float*)d_out;

  // ws: many (128KB) | xt bf16 (15.0MB) | wt bf16 (1.2MB)  => ~17.1MB total
  unsigned char*  many = (unsigned char*)d_ws;
  unsigned short* xt   = (unsigned short*)((char*)d_ws + 131072);
  unsigned short* wt   = (unsigned short*)((char*)d_ws + 131072 + (size_t)NB * HH * XT_IY * 2);

  pool_mask_k<<<(NB * OHH * OWW + 255) / 256, 256, 0, stream>>>(mask, many);
  xpose_k<<<NB * HH, 256, 0, stream>>>(x, xt);
  wpack_k<<<(CIN * COUT + 255) / 256, 256, 0, stream>>>(w, wt);
  convt_mfma<<<NB * OHH, 256, 0, stream>>>(xt, wt, bias, many, out);
}